// Round 1
// baseline (16025.085 us; speedup 1.0000x reference)
//
#include <hip/hip_runtime.h>
#include <math.h>

#define NUM_USERS 100000
#define NUM_ITEMS 50000
#define EMBED     64
#define NUM_EDGES 3276800
#define BATCH     16384

// ---- degree ----
__global__ void deg_kernel(const int* __restrict__ rows, float* __restrict__ deg) {
    int e = blockIdx.x * blockDim.x + threadIdx.x;
    if (e < NUM_EDGES) atomicAdd(&deg[rows[e]], 1.0f);
}

__global__ void invdeg_kernel(float* __restrict__ deg) {
    int i = blockIdx.x * blockDim.x + threadIdx.x;
    if (i < NUM_USERS) {
        float d = deg[i];
        deg[i] = d > 0.0f ? 1.0f / d : 0.0f;
    }
}

// ---- u[rows[e]] += invdeg[rows[e]] * it[cols[e]]  (16 threads/edge, float4 each) ----
__global__ void scatter_u_kernel(const int* __restrict__ rows, const int* __restrict__ cols,
                                 const float* __restrict__ invdeg,
                                 const float* __restrict__ it, float* __restrict__ u) {
    long long tid = (long long)blockIdx.x * blockDim.x + threadIdx.x;
    int e = (int)(tid >> 4);
    int q = (int)(tid & 15);
    if (e >= NUM_EDGES) return;
    int row = rows[e];
    int col = cols[e];
    float v = invdeg[row];
    const float4* src = (const float4*)(it + (long long)col * EMBED);
    float4 x = src[q];
    float* dst = u + (long long)row * EMBED + q * 4;
    atomicAdd(dst + 0, v * x.x);
    atomicAdd(dst + 1, v * x.y);
    atomicAdd(dst + 2, v * x.z);
    atomicAdd(dst + 3, v * x.w);
}

// ---- it[cols[e]] += invdeg[rows[e]] * u[rows[e]] ----
__global__ void scatter_it_kernel(const int* __restrict__ rows, const int* __restrict__ cols,
                                  const float* __restrict__ invdeg,
                                  const float* __restrict__ u, float* __restrict__ it) {
    long long tid = (long long)blockIdx.x * blockDim.x + threadIdx.x;
    int e = (int)(tid >> 4);
    int q = (int)(tid & 15);
    if (e >= NUM_EDGES) return;
    int row = rows[e];
    int col = cols[e];
    float v = invdeg[row];
    const float4* src = (const float4*)(u + (long long)row * EMBED);
    float4 x = src[q];
    float* dst = it + (long long)col * EMBED + q * 4;
    atomicAdd(dst + 0, v * x.x);
    atomicAdd(dst + 1, v * x.y);
    atomicAdd(dst + 2, v * x.z);
    atomicAdd(dst + 3, v * x.w);
}

// ---- scores: one 64-lane wave per batch element ----
__global__ void score_kernel(const float* __restrict__ u, const float* __restrict__ it,
                             const int* __restrict__ uidx, const int* __restrict__ iidx,
                             float* __restrict__ out) {
    int wave_in_block = threadIdx.x >> 6;   // 4 waves per 256-thread block
    int lane = threadIdx.x & 63;
    int b = blockIdx.x * 4 + wave_in_block;
    if (b >= BATCH) return;
    int ui = uidx[b];
    int ii = iidx[b];
    float s = u[(long long)ui * EMBED + lane] * it[(long long)ii * EMBED + lane];
    #pragma unroll
    for (int off = 32; off > 0; off >>= 1)
        s += __shfl_down(s, off, 64);
    if (lane == 0)
        out[b] = 1.0f / (1.0f + expf(-s));
}

extern "C" void kernel_launch(void* const* d_in, const int* in_sizes, int n_in,
                              void* d_out, int out_size, void* d_ws, size_t ws_size,
                              hipStream_t stream) {
    // input order: user_table, item_table, rows, cols, user_indices, item_indices
    const float* item_table = (const float*)d_in[1];
    const int*   rows       = (const int*)d_in[2];
    const int*   cols       = (const int*)d_in[3];
    const int*   uidx       = (const int*)d_in[4];
    const int*   iidx       = (const int*)d_in[5];
    float* out = (float*)d_out;

    float* ws     = (float*)d_ws;
    float* invdeg = ws;                                  // NUM_USERS floats
    float* u      = ws + NUM_USERS;                      // NUM_USERS*64 floats (offset 400000B, 16B-aligned)
    float* it     = u + (long long)NUM_USERS * EMBED;    // NUM_ITEMS*64 floats

    // degree -> inv_deg (in place)
    hipMemsetAsync(invdeg, 0, NUM_USERS * sizeof(float), stream);
    deg_kernel<<<(NUM_EDGES + 255) / 256, 256, 0, stream>>>(rows, invdeg);
    invdeg_kernel<<<(NUM_USERS + 255) / 256, 256, 0, stream>>>(invdeg);

    const int scatter_blocks = (NUM_EDGES * 16) / 256;   // 204800, exact
    for (int l = 0; l < 3; ++l) {
        hipMemsetAsync(u, 0, (size_t)NUM_USERS * EMBED * sizeof(float), stream);
        scatter_u_kernel<<<scatter_blocks, 256, 0, stream>>>(
            rows, cols, invdeg, (l == 0) ? item_table : it, u);
        hipMemsetAsync(it, 0, (size_t)NUM_ITEMS * EMBED * sizeof(float), stream);
        scatter_it_kernel<<<scatter_blocks, 256, 0, stream>>>(rows, cols, invdeg, u, it);
    }

    score_kernel<<<BATCH / 4, 256, 0, stream>>>(u, it, uidx, iidx, out);
}

// Round 2
// 1669.375 us; speedup vs baseline: 9.5995x; 9.5995x over previous
//
#include <hip/hip_runtime.h>
#include <math.h>

#define NUM_USERS 100000
#define NUM_ITEMS 50000
#define EMBED     64
#define NUM_EDGES 3276800
#define BATCH     16384

// ---------- degree counting (int atomics, cheap) ----------
__global__ void count_kernel(const int* __restrict__ rows, const int* __restrict__ cols,
                             int* __restrict__ udeg, int* __restrict__ ideg) {
    int e = blockIdx.x * blockDim.x + threadIdx.x;
    if (e < NUM_EDGES) {
        atomicAdd(&udeg[rows[e]], 1);
        atomicAdd(&ideg[cols[e]], 1);
    }
}

__global__ void invdeg_kernel(const int* __restrict__ udeg, float* __restrict__ invdeg) {
    int i = blockIdx.x * blockDim.x + threadIdx.x;
    if (i < NUM_USERS) {
        int d = udeg[i];
        invdeg[i] = d > 0 ? 1.0f / (float)d : 0.0f;
    }
}

// ---------- hierarchical exclusive scan ----------
__global__ void scan_block(const int* __restrict__ in, int* __restrict__ out,
                           int* __restrict__ bsums, int n) {
    __shared__ int s[256];
    int i = blockIdx.x * 256 + threadIdx.x;
    int v = (i < n) ? in[i] : 0;
    s[threadIdx.x] = v;
    __syncthreads();
    for (int off = 1; off < 256; off <<= 1) {
        int t = (threadIdx.x >= off) ? s[threadIdx.x - off] : 0;
        __syncthreads();
        s[threadIdx.x] += t;
        __syncthreads();
    }
    if (i < n) out[i] = s[threadIdx.x] - v;          // exclusive
    if (threadIdx.x == 255) bsums[blockIdx.x] = s[255];
}

__global__ void scan_sums(int* __restrict__ bsums, int nb) {
    if (blockIdx.x == 0 && threadIdx.x == 0) {
        int acc = 0;
        for (int i = 0; i < nb; ++i) { int t = bsums[i]; bsums[i] = acc; acc += t; }
    }
}

__global__ void scan_add(int* __restrict__ out, const int* __restrict__ bsums, int n) {
    int i = blockIdx.x * 256 + threadIdx.x;
    if (i < n) out[i] += bsums[blockIdx.x];
}

// ---------- fill CSR (user -> cols) and CSC (item -> rows) ----------
__global__ void fill_kernel(const int* __restrict__ rows, const int* __restrict__ cols,
                            const int* __restrict__ uoff, int* __restrict__ ucur,
                            const int* __restrict__ ioff, int* __restrict__ icur,
                            int* __restrict__ csr_col, int* __restrict__ csc_row) {
    int e = blockIdx.x * blockDim.x + threadIdx.x;
    if (e >= NUM_EDGES) return;
    int r = rows[e];
    int c = cols[e];
    int p = uoff[r] + atomicAdd(&ucur[r], 1);
    csr_col[p] = c;
    int q = ioff[c] + atomicAdd(&icur[c], 1);
    csc_row[q] = r;
}

// ---------- gather SpMM: u[row] = invdeg[row] * sum_{e in row} it[col_e] ----------
__global__ void gather_u(const int* __restrict__ uoff, const int* __restrict__ udeg,
                         const int* __restrict__ csr_col, const float* __restrict__ invdeg,
                         const float* __restrict__ it, float* __restrict__ u) {
    int wave = (blockIdx.x * blockDim.x + threadIdx.x) >> 6;
    int lane = threadIdx.x & 63;
    int row = __builtin_amdgcn_readfirstlane(wave);
    if (row >= NUM_USERS) return;
    int start = uoff[row];
    int end = start + udeg[row];
    float s = 0.0f;
    int k = start;
    for (; k + 3 < end; k += 4) {
        int c0 = csr_col[k + 0], c1 = csr_col[k + 1];
        int c2 = csr_col[k + 2], c3 = csr_col[k + 3];
        float a0 = it[c0 * EMBED + lane];
        float a1 = it[c1 * EMBED + lane];
        float a2 = it[c2 * EMBED + lane];
        float a3 = it[c3 * EMBED + lane];
        s += a0 + a1 + a2 + a3;
    }
    for (; k < end; ++k) s += it[csr_col[k] * EMBED + lane];
    u[row * EMBED + lane] = invdeg[row] * s;
}

// ---------- gather SpMM: it[col] = sum_{e in col} invdeg[row_e] * u[row_e] ----------
__global__ void gather_it(const int* __restrict__ ioff, const int* __restrict__ ideg,
                          const int* __restrict__ csc_row, const float* __restrict__ invdeg,
                          const float* __restrict__ u, float* __restrict__ it) {
    int wave = (blockIdx.x * blockDim.x + threadIdx.x) >> 6;
    int lane = threadIdx.x & 63;
    int col = __builtin_amdgcn_readfirstlane(wave);
    if (col >= NUM_ITEMS) return;
    int start = ioff[col];
    int end = start + ideg[col];
    float s = 0.0f;
    int k = start;
    for (; k + 3 < end; k += 4) {
        int r0 = csc_row[k + 0], r1 = csc_row[k + 1];
        int r2 = csc_row[k + 2], r3 = csc_row[k + 3];
        float v0 = invdeg[r0], v1 = invdeg[r1], v2 = invdeg[r2], v3 = invdeg[r3];
        float a0 = u[r0 * EMBED + lane];
        float a1 = u[r1 * EMBED + lane];
        float a2 = u[r2 * EMBED + lane];
        float a3 = u[r3 * EMBED + lane];
        s += v0 * a0 + v1 * a1 + v2 * a2 + v3 * a3;
    }
    for (; k < end; ++k) {
        int r = csc_row[k];
        s += invdeg[r] * u[r * EMBED + lane];
    }
    it[col * EMBED + lane] = s;
}

// ---------- scores ----------
__global__ void score_kernel(const float* __restrict__ u, const float* __restrict__ it,
                             const int* __restrict__ uidx, const int* __restrict__ iidx,
                             float* __restrict__ out) {
    int wave_in_block = threadIdx.x >> 6;
    int lane = threadIdx.x & 63;
    int b = blockIdx.x * 4 + wave_in_block;
    if (b >= BATCH) return;
    int ui = uidx[b];
    int ii = iidx[b];
    float s = u[(long long)ui * EMBED + lane] * it[(long long)ii * EMBED + lane];
    #pragma unroll
    for (int off = 32; off > 0; off >>= 1)
        s += __shfl_down(s, off, 64);
    if (lane == 0)
        out[b] = 1.0f / (1.0f + expf(-s));
}

extern "C" void kernel_launch(void* const* d_in, const int* in_sizes, int n_in,
                              void* d_out, int out_size, void* d_ws, size_t ws_size,
                              hipStream_t stream) {
    const float* item_table = (const float*)d_in[1];
    const int*   rows       = (const int*)d_in[2];
    const int*   cols       = (const int*)d_in[3];
    const int*   uidx       = (const int*)d_in[4];
    const int*   iidx       = (const int*)d_in[5];
    float* out = (float*)d_out;

    // workspace layout (4-byte elements)
    char* base = (char*)d_ws;
    float* invdeg  = (float*)(base);                          // 100000
    int*   udeg    = (int*)(base + 4LL *   100000);           // 100000
    int*   ideg    = (int*)(base + 4LL *   200000);           // 50000
    int*   uoff    = (int*)(base + 4LL *   250000);           // 100000
    int*   ioff    = (int*)(base + 4LL *   350000);           // 50000
    int*   ucur    = (int*)(base + 4LL *   400000);           // 100000
    int*   icur    = (int*)(base + 4LL *   500000);           // 50000
    int*   bsums   = (int*)(base + 4LL *   550000);           // 2048
    int*   csr_col = (int*)(base + 4LL *   552048);           // NUM_EDGES
    int*   csc_row = (int*)(base + 4LL *  3828848);           // NUM_EDGES
    float* u       = (float*)(base + 4LL * 7105648);          // 100000*64
    float* it      = (float*)(base + 4LL * 13505648);         // 50000*64
    // total: 16705648 * 4 B ~= 67 MB

    // zero the counters (udeg+ideg contiguous; ucur+icur contiguous)
    hipMemsetAsync(udeg, 0, 150000 * sizeof(int), stream);
    hipMemsetAsync(ucur, 0, 150000 * sizeof(int), stream);

    const int eblocks = (NUM_EDGES + 255) / 256;
    count_kernel<<<eblocks, 256, 0, stream>>>(rows, cols, udeg, ideg);
    invdeg_kernel<<<(NUM_USERS + 255) / 256, 256, 0, stream>>>(udeg, invdeg);

    // exclusive scan of udeg -> uoff
    int nb_u = (NUM_USERS + 255) / 256;   // 391
    scan_block<<<nb_u, 256, 0, stream>>>(udeg, uoff, bsums, NUM_USERS);
    scan_sums<<<1, 64, 0, stream>>>(bsums, nb_u);
    scan_add<<<nb_u, 256, 0, stream>>>(uoff, bsums, NUM_USERS);
    // exclusive scan of ideg -> ioff
    int nb_i = (NUM_ITEMS + 255) / 256;   // 196
    scan_block<<<nb_i, 256, 0, stream>>>(ideg, ioff, bsums, NUM_ITEMS);
    scan_sums<<<1, 64, 0, stream>>>(bsums, nb_i);
    scan_add<<<nb_i, 256, 0, stream>>>(ioff, bsums, NUM_ITEMS);

    fill_kernel<<<eblocks, 256, 0, stream>>>(rows, cols, uoff, ucur, ioff, icur,
                                             csr_col, csc_row);

    const int ublocks = (NUM_USERS + 3) / 4;   // 4 waves per block
    const int iblocks = (NUM_ITEMS + 3) / 4;
    for (int l = 0; l < 3; ++l) {
        gather_u<<<ublocks, 256, 0, stream>>>(uoff, udeg, csr_col, invdeg,
                                              (l == 0) ? item_table : it, u);
        gather_it<<<iblocks, 256, 0, stream>>>(ioff, ideg, csc_row, invdeg, u, it);
    }

    score_kernel<<<BATCH / 4, 256, 0, stream>>>(u, it, uidx, iidx, out);
}

// Round 3
// 1625.535 us; speedup vs baseline: 9.8583x; 1.0270x over previous
//
#include <hip/hip_runtime.h>
#include <math.h>

#define NUM_USERS 100000
#define NUM_ITEMS 50000
#define EMBED     64
#define NUM_EDGES 3276800
#define BATCH     16384

// ---------- degree counting (int atomics) ----------
__global__ void count_kernel(const int* __restrict__ rows, const int* __restrict__ cols,
                             int* __restrict__ udeg, int* __restrict__ ideg) {
    int e = blockIdx.x * blockDim.x + threadIdx.x;
    if (e < NUM_EDGES) {
        atomicAdd(&udeg[rows[e]], 1);
        atomicAdd(&ideg[cols[e]], 1);
    }
}

__global__ void invdeg_kernel(const int* __restrict__ udeg, float* __restrict__ invdeg) {
    int i = blockIdx.x * blockDim.x + threadIdx.x;
    if (i < NUM_USERS) {
        int d = udeg[i];
        invdeg[i] = d > 0 ? 1.0f / (float)d : 0.0f;
    }
}

// ---------- hierarchical exclusive scan ----------
__global__ void scan_block(const int* __restrict__ in, int* __restrict__ out,
                           int* __restrict__ bsums, int n) {
    __shared__ int s[256];
    int i = blockIdx.x * 256 + threadIdx.x;
    int v = (i < n) ? in[i] : 0;
    s[threadIdx.x] = v;
    __syncthreads();
    for (int off = 1; off < 256; off <<= 1) {
        int t = (threadIdx.x >= off) ? s[threadIdx.x - off] : 0;
        __syncthreads();
        s[threadIdx.x] += t;
        __syncthreads();
    }
    if (i < n) out[i] = s[threadIdx.x] - v;          // exclusive
    if (threadIdx.x == 255) bsums[blockIdx.x] = s[255];
}

__global__ void scan_sums(int* __restrict__ bsums, int nb) {
    if (blockIdx.x == 0 && threadIdx.x == 0) {
        int acc = 0;
        for (int i = 0; i < nb; ++i) { int t = bsums[i]; bsums[i] = acc; acc += t; }
    }
}

__global__ void scan_add(int* __restrict__ out, const int* __restrict__ bsums, int n) {
    int i = blockIdx.x * 256 + threadIdx.x;
    if (i < n) out[i] += bsums[blockIdx.x];
}

// ---------- XCD-classed CSR/CSC fill ----------
// Output position granules of 1 KB (256 ints) are classed by (off>>8)&7.
// Block with blockIdx.x%8==cls (round-robin XCD mapping heuristic) writes only
// class-cls granules, so each 64B line collects all its writes in ONE XCD's L2.
__global__ void fill_kernel(const int* __restrict__ rows, const int* __restrict__ cols,
                            const int* __restrict__ uoff, int* __restrict__ ucur,
                            const int* __restrict__ ioff, int* __restrict__ icur,
                            int* __restrict__ csr_col, int* __restrict__ csc_row) {
    int cls = blockIdx.x & 7;
    int grp = blockIdx.x >> 3;
    int stride = (gridDim.x >> 3) * blockDim.x;
    for (int e = grp * blockDim.x + threadIdx.x; e < NUM_EDGES; e += stride) {
        int r = rows[e];
        int c = cols[e];
        int ub = uoff[r];
        if (((ub >> 8) & 7) == cls) {
            int p = ub + atomicAdd(&ucur[r], 1);
            csr_col[p] = c;
        }
        int ib = ioff[c];
        if (((ib >> 8) & 7) == cls) {
            int q = ib + atomicAdd(&icur[c], 1);
            csc_row[q] = r;
        }
    }
}

// ---------- gather SpMM (u): wave = row, 4 edge-slots x 16 lanes x float4 ----------
__global__ void gather_u(const int* __restrict__ uoff, const int* __restrict__ udeg,
                         const int* __restrict__ csr_col, const float* __restrict__ invdeg,
                         const float* __restrict__ it, float* __restrict__ u) {
    int row = blockIdx.x * 4 + (threadIdx.x >> 6);
    if (row >= NUM_USERS) return;
    int lane = threadIdx.x & 63;
    int sub = lane >> 4;        // edge slot 0..3
    int d4  = lane & 15;        // which float4 of the 64-dim row
    int start = uoff[row];
    int end = start + udeg[row];
    float4 acc = make_float4(0.f, 0.f, 0.f, 0.f);
    for (int k = start; k < end; k += 4) {
        int idx = k + sub;
        int safe = idx < end ? idx : end - 1;
        int c = csr_col[safe];
        const float4 x = *(const float4*)(it + (long long)c * EMBED + (d4 << 2));
        if (idx < end) {
            acc.x += x.x; acc.y += x.y; acc.z += x.z; acc.w += x.w;
        }
    }
    // reduce across the 4 edge slots (xor 16, then 32)
    acc.x += __shfl_xor(acc.x, 16, 64); acc.y += __shfl_xor(acc.y, 16, 64);
    acc.z += __shfl_xor(acc.z, 16, 64); acc.w += __shfl_xor(acc.w, 16, 64);
    acc.x += __shfl_xor(acc.x, 32, 64); acc.y += __shfl_xor(acc.y, 32, 64);
    acc.z += __shfl_xor(acc.z, 32, 64); acc.w += __shfl_xor(acc.w, 32, 64);
    if (lane < 16) {
        float v = invdeg[row];
        acc.x *= v; acc.y *= v; acc.z *= v; acc.w *= v;
        *(float4*)(u + (long long)row * EMBED + (lane << 2)) = acc;
    }
}

// ---------- gather SpMM (it): same structure, per-edge invdeg weight ----------
__global__ void gather_it(const int* __restrict__ ioff, const int* __restrict__ ideg,
                          const int* __restrict__ csc_row, const float* __restrict__ invdeg,
                          const float* __restrict__ u, float* __restrict__ it) {
    int col = blockIdx.x * 4 + (threadIdx.x >> 6);
    if (col >= NUM_ITEMS) return;
    int lane = threadIdx.x & 63;
    int sub = lane >> 4;
    int d4  = lane & 15;
    int start = ioff[col];
    int end = start + ideg[col];
    float4 acc = make_float4(0.f, 0.f, 0.f, 0.f);
    for (int k = start; k < end; k += 4) {
        int idx = k + sub;
        int safe = idx < end ? idx : end - 1;
        int r = csc_row[safe];
        float v = invdeg[r];
        const float4 x = *(const float4*)(u + (long long)r * EMBED + (d4 << 2));
        if (idx < end) {
            acc.x += v * x.x; acc.y += v * x.y; acc.z += v * x.z; acc.w += v * x.w;
        }
    }
    acc.x += __shfl_xor(acc.x, 16, 64); acc.y += __shfl_xor(acc.y, 16, 64);
    acc.z += __shfl_xor(acc.z, 16, 64); acc.w += __shfl_xor(acc.w, 16, 64);
    acc.x += __shfl_xor(acc.x, 32, 64); acc.y += __shfl_xor(acc.y, 32, 64);
    acc.z += __shfl_xor(acc.z, 32, 64); acc.w += __shfl_xor(acc.w, 32, 64);
    if (lane < 16)
        *(float4*)(it + (long long)col * EMBED + (lane << 2)) = acc;
}

// ---------- scores ----------
__global__ void score_kernel(const float* __restrict__ u, const float* __restrict__ it,
                             const int* __restrict__ uidx, const int* __restrict__ iidx,
                             float* __restrict__ out) {
    int wave_in_block = threadIdx.x >> 6;
    int lane = threadIdx.x & 63;
    int b = blockIdx.x * 4 + wave_in_block;
    if (b >= BATCH) return;
    int ui = uidx[b];
    int ii = iidx[b];
    float s = u[(long long)ui * EMBED + lane] * it[(long long)ii * EMBED + lane];
    #pragma unroll
    for (int off = 32; off > 0; off >>= 1)
        s += __shfl_down(s, off, 64);
    if (lane == 0)
        out[b] = 1.0f / (1.0f + expf(-s));
}

extern "C" void kernel_launch(void* const* d_in, const int* in_sizes, int n_in,
                              void* d_out, int out_size, void* d_ws, size_t ws_size,
                              hipStream_t stream) {
    const float* item_table = (const float*)d_in[1];
    const int*   rows       = (const int*)d_in[2];
    const int*   cols       = (const int*)d_in[3];
    const int*   uidx       = (const int*)d_in[4];
    const int*   iidx       = (const int*)d_in[5];
    float* out = (float*)d_out;

    // workspace layout (4-byte elements)
    char* base = (char*)d_ws;
    float* invdeg  = (float*)(base);                          // 100000
    int*   udeg    = (int*)(base + 4LL *   100000);           // 100000
    int*   ideg    = (int*)(base + 4LL *   200000);           // 50000
    int*   uoff    = (int*)(base + 4LL *   250000);           // 100000
    int*   ioff    = (int*)(base + 4LL *   350000);           // 50000
    int*   ucur    = (int*)(base + 4LL *   400000);           // 100000
    int*   icur    = (int*)(base + 4LL *   500000);           // 50000
    int*   bsums   = (int*)(base + 4LL *   550000);           // 2048
    int*   csr_col = (int*)(base + 4LL *   552048);           // NUM_EDGES
    int*   csc_row = (int*)(base + 4LL *  3828848);           // NUM_EDGES
    float* u       = (float*)(base + 4LL * 7105648);          // 100000*64
    float* it      = (float*)(base + 4LL * 13505648);         // 50000*64

    hipMemsetAsync(udeg, 0, 150000 * sizeof(int), stream);
    hipMemsetAsync(ucur, 0, 150000 * sizeof(int), stream);

    const int eblocks = (NUM_EDGES + 255) / 256;
    count_kernel<<<eblocks, 256, 0, stream>>>(rows, cols, udeg, ideg);
    invdeg_kernel<<<(NUM_USERS + 255) / 256, 256, 0, stream>>>(udeg, invdeg);

    int nb_u = (NUM_USERS + 255) / 256;   // 391
    scan_block<<<nb_u, 256, 0, stream>>>(udeg, uoff, bsums, NUM_USERS);
    scan_sums<<<1, 64, 0, stream>>>(bsums, nb_u);
    scan_add<<<nb_u, 256, 0, stream>>>(uoff, bsums, NUM_USERS);
    int nb_i = (NUM_ITEMS + 255) / 256;   // 196
    scan_block<<<nb_i, 256, 0, stream>>>(ideg, ioff, bsums, NUM_ITEMS);
    scan_sums<<<1, 64, 0, stream>>>(bsums, nb_i);
    scan_add<<<nb_i, 256, 0, stream>>>(ioff, bsums, NUM_ITEMS);

    fill_kernel<<<2048, 256, 0, stream>>>(rows, cols, uoff, ucur, ioff, icur,
                                          csr_col, csc_row);

    const int ublocks = (NUM_USERS + 3) / 4;   // 4 waves (rows) per block
    const int iblocks = (NUM_ITEMS + 3) / 4;
    for (int l = 0; l < 3; ++l) {
        gather_u<<<ublocks, 256, 0, stream>>>(uoff, udeg, csr_col, invdeg,
                                              (l == 0) ? item_table : it, u);
        gather_it<<<iblocks, 256, 0, stream>>>(ioff, ideg, csc_row, invdeg, u, it);
    }

    score_kernel<<<BATCH / 4, 256, 0, stream>>>(u, it, uidx, iidx, out);
}

// Round 4
// 1574.149 us; speedup vs baseline: 10.1802x; 1.0326x over previous
//
#include <hip/hip_runtime.h>
#include <math.h>

#define NUM_USERS 100000
#define NUM_ITEMS 50000
#define EMBED     64
#define NUM_EDGES 3276800
#define BATCH     16384

typedef _Float16 half8 __attribute__((ext_vector_type(8)));

// ---------- degree counting (int atomics) ----------
__global__ void count_kernel(const int* __restrict__ rows, const int* __restrict__ cols,
                             int* __restrict__ udeg, int* __restrict__ ideg) {
    int e = blockIdx.x * blockDim.x + threadIdx.x;
    if (e < NUM_EDGES) {
        atomicAdd(&udeg[__builtin_nontemporal_load(&rows[e])], 1);
        atomicAdd(&ideg[__builtin_nontemporal_load(&cols[e])], 1);
    }
}

__global__ void invdeg_kernel(const int* __restrict__ udeg, float* __restrict__ invdeg) {
    int i = blockIdx.x * blockDim.x + threadIdx.x;
    if (i < NUM_USERS) {
        int d = udeg[i];
        invdeg[i] = d > 0 ? 1.0f / (float)d : 0.0f;
    }
}

// ---------- item_table fp32 -> fp16 ----------
__global__ void cvt_kernel(const float* __restrict__ in, _Float16* __restrict__ out, int n8) {
    int i = blockIdx.x * 256 + threadIdx.x;
    if (i >= n8) return;
    const float4* p = (const float4*)in + 2 * i;
    float4 a = p[0], b = p[1];
    half8 o;
    o[0] = (_Float16)a.x; o[1] = (_Float16)a.y; o[2] = (_Float16)a.z; o[3] = (_Float16)a.w;
    o[4] = (_Float16)b.x; o[5] = (_Float16)b.y; o[6] = (_Float16)b.z; o[7] = (_Float16)b.w;
    ((half8*)out)[i] = o;
}

// ---------- hierarchical exclusive scan ----------
__global__ void scan_block(const int* __restrict__ in, int* __restrict__ out,
                           int* __restrict__ bsums, int n) {
    __shared__ int s[256];
    int i = blockIdx.x * 256 + threadIdx.x;
    int v = (i < n) ? in[i] : 0;
    s[threadIdx.x] = v;
    __syncthreads();
    for (int off = 1; off < 256; off <<= 1) {
        int t = (threadIdx.x >= off) ? s[threadIdx.x - off] : 0;
        __syncthreads();
        s[threadIdx.x] += t;
        __syncthreads();
    }
    if (i < n) out[i] = s[threadIdx.x] - v;          // exclusive
    if (threadIdx.x == 255) bsums[blockIdx.x] = s[255];
}

__global__ void scan_sums(int* __restrict__ bsums, int nb) {
    if (blockIdx.x == 0 && threadIdx.x == 0) {
        int acc = 0;
        for (int i = 0; i < nb; ++i) { int t = bsums[i]; bsums[i] = acc; acc += t; }
    }
}

__global__ void scan_add(int* __restrict__ out, const int* __restrict__ bsums, int n) {
    int i = blockIdx.x * 256 + threadIdx.x;
    if (i < n) out[i] += bsums[blockIdx.x];
}

// ---------- XCD-classed CSR/CSC fill, non-temporal index streams ----------
__global__ void fill_kernel(const int* __restrict__ rows, const int* __restrict__ cols,
                            const int* __restrict__ uoff, int* __restrict__ ucur,
                            const int* __restrict__ ioff, int* __restrict__ icur,
                            int* __restrict__ csr_col, int* __restrict__ csc_row) {
    int cls = blockIdx.x & 7;
    int grp = blockIdx.x >> 3;
    int stride = (gridDim.x >> 3) * blockDim.x;
    for (int e = grp * blockDim.x + threadIdx.x; e < NUM_EDGES; e += stride) {
        int r = __builtin_nontemporal_load(&rows[e]);
        int c = __builtin_nontemporal_load(&cols[e]);
        int ub = uoff[r];
        if (((ub >> 8) & 7) == cls) {
            int p = ub + atomicAdd(&ucur[r], 1);
            csr_col[p] = c;
        }
        int ib = ioff[c];
        if (((ib >> 8) & 7) == cls) {
            int q = ib + atomicAdd(&icur[c], 1);
            csc_row[q] = r;
        }
    }
}

// ---------- gather SpMM (u): wave = row, 8 edge-slots x 8 lanes x half8 ----------
__global__ void gather_u(const int* __restrict__ uoff, const int* __restrict__ udeg,
                         const int* __restrict__ csr_col, const float* __restrict__ invdeg,
                         const _Float16* __restrict__ it, _Float16* __restrict__ u) {
    int row = blockIdx.x * 4 + (threadIdx.x >> 6);
    if (row >= NUM_USERS) return;
    int lane = threadIdx.x & 63;
    int slot = lane >> 3;       // edge slot 0..7
    int h    = lane & 7;        // which half8 of the 64-dim row
    int start = uoff[row];
    int end = start + udeg[row];
    float acc[8] = {0.f, 0.f, 0.f, 0.f, 0.f, 0.f, 0.f, 0.f};
    for (int k = start; k < end; k += 8) {
        int idx = k + slot;
        int safe = idx < end ? idx : end - 1;
        int c = __builtin_nontemporal_load(&csr_col[safe]);
        half8 x = *(const half8*)(it + (long long)c * EMBED + (h << 3));
        if (idx < end) {
            #pragma unroll
            for (int j = 0; j < 8; ++j) acc[j] += (float)x[j];
        }
    }
    #pragma unroll
    for (int j = 0; j < 8; ++j) {
        acc[j] += __shfl_xor(acc[j], 8, 64);
        acc[j] += __shfl_xor(acc[j], 16, 64);
        acc[j] += __shfl_xor(acc[j], 32, 64);
    }
    if (lane < 8) {
        float v = invdeg[row];
        half8 o;
        #pragma unroll
        for (int j = 0; j < 8; ++j) o[j] = (_Float16)(acc[j] * v);
        *(half8*)(u + (long long)row * EMBED + (lane << 3)) = o;
    }
}

// ---------- gather SpMM (it): per-edge invdeg weight ----------
__global__ void gather_it(const int* __restrict__ ioff, const int* __restrict__ ideg,
                          const int* __restrict__ csc_row, const float* __restrict__ invdeg,
                          const _Float16* __restrict__ u, _Float16* __restrict__ it) {
    int col = blockIdx.x * 4 + (threadIdx.x >> 6);
    if (col >= NUM_ITEMS) return;
    int lane = threadIdx.x & 63;
    int slot = lane >> 3;
    int h    = lane & 7;
    int start = ioff[col];
    int end = start + ideg[col];
    float acc[8] = {0.f, 0.f, 0.f, 0.f, 0.f, 0.f, 0.f, 0.f};
    for (int k = start; k < end; k += 8) {
        int idx = k + slot;
        int safe = idx < end ? idx : end - 1;
        int r = __builtin_nontemporal_load(&csc_row[safe]);
        float v = invdeg[r];
        half8 x = *(const half8*)(u + (long long)r * EMBED + (h << 3));
        if (idx < end) {
            #pragma unroll
            for (int j = 0; j < 8; ++j) acc[j] += v * (float)x[j];
        }
    }
    #pragma unroll
    for (int j = 0; j < 8; ++j) {
        acc[j] += __shfl_xor(acc[j], 8, 64);
        acc[j] += __shfl_xor(acc[j], 16, 64);
        acc[j] += __shfl_xor(acc[j], 32, 64);
    }
    if (lane < 8) {
        half8 o;
        #pragma unroll
        for (int j = 0; j < 8; ++j) o[j] = (_Float16)acc[j];
        *(half8*)(it + (long long)col * EMBED + (lane << 3)) = o;
    }
}

// ---------- scores ----------
__global__ void score_kernel(const _Float16* __restrict__ u, const _Float16* __restrict__ it,
                             const int* __restrict__ uidx, const int* __restrict__ iidx,
                             float* __restrict__ out) {
    int wave_in_block = threadIdx.x >> 6;
    int lane = threadIdx.x & 63;
    int b = blockIdx.x * 4 + wave_in_block;
    if (b >= BATCH) return;
    int ui = uidx[b];
    int ii = iidx[b];
    float s = (float)u[(long long)ui * EMBED + lane] * (float)it[(long long)ii * EMBED + lane];
    #pragma unroll
    for (int off = 32; off > 0; off >>= 1)
        s += __shfl_down(s, off, 64);
    if (lane == 0)
        out[b] = 1.0f / (1.0f + expf(-s));
}

extern "C" void kernel_launch(void* const* d_in, const int* in_sizes, int n_in,
                              void* d_out, int out_size, void* d_ws, size_t ws_size,
                              hipStream_t stream) {
    const float* item_table = (const float*)d_in[1];
    const int*   rows       = (const int*)d_in[2];
    const int*   cols       = (const int*)d_in[3];
    const int*   uidx       = (const int*)d_in[4];
    const int*   iidx       = (const int*)d_in[5];
    float* out = (float*)d_out;

    // workspace layout (byte offsets in units of 4B where noted)
    char* base = (char*)d_ws;
    float*     invdeg  = (float*)(base);                       // 100000
    int*       udeg    = (int*)(base + 4LL *   100000);        // 100000
    int*       ideg    = (int*)(base + 4LL *   200000);        // 50000
    int*       uoff    = (int*)(base + 4LL *   250000);        // 100000
    int*       ioff    = (int*)(base + 4LL *   350000);        // 50000
    int*       ucur    = (int*)(base + 4LL *   400000);        // 100000
    int*       icur    = (int*)(base + 4LL *   500000);        // 50000
    int*       bsums   = (int*)(base + 4LL *   550000);        // 2048
    int*       csr_col = (int*)(base + 4LL *   552048);        // NUM_EDGES
    int*       csc_row = (int*)(base + 4LL *  3828848);        // NUM_EDGES
    _Float16*  u16     = (_Float16*)(base + 4LL * 7105648);            // 100000*64 halves (12.8 MB)
    _Float16*  it16    = (_Float16*)(base + 4LL * 7105648 + 12800000); // 50000*64 halves (6.4 MB)

    hipMemsetAsync(udeg, 0, 150000 * sizeof(int), stream);
    hipMemsetAsync(ucur, 0, 150000 * sizeof(int), stream);

    const int eblocks = (NUM_EDGES + 255) / 256;
    count_kernel<<<eblocks, 256, 0, stream>>>(rows, cols, udeg, ideg);
    invdeg_kernel<<<(NUM_USERS + 255) / 256, 256, 0, stream>>>(udeg, invdeg);
    cvt_kernel<<<(NUM_ITEMS * EMBED / 8 + 255) / 256, 256, 0, stream>>>(
        item_table, it16, NUM_ITEMS * EMBED / 8);

    int nb_u = (NUM_USERS + 255) / 256;   // 391
    scan_block<<<nb_u, 256, 0, stream>>>(udeg, uoff, bsums, NUM_USERS);
    scan_sums<<<1, 64, 0, stream>>>(bsums, nb_u);
    scan_add<<<nb_u, 256, 0, stream>>>(uoff, bsums, NUM_USERS);
    int nb_i = (NUM_ITEMS + 255) / 256;   // 196
    scan_block<<<nb_i, 256, 0, stream>>>(ideg, ioff, bsums, NUM_ITEMS);
    scan_sums<<<1, 64, 0, stream>>>(bsums, nb_i);
    scan_add<<<nb_i, 256, 0, stream>>>(ioff, bsums, NUM_ITEMS);

    fill_kernel<<<2048, 256, 0, stream>>>(rows, cols, uoff, ucur, ioff, icur,
                                          csr_col, csc_row);

    const int ublocks = (NUM_USERS + 3) / 4;   // 4 waves (rows) per block
    const int iblocks = (NUM_ITEMS + 3) / 4;
    for (int l = 0; l < 3; ++l) {
        gather_u<<<ublocks, 256, 0, stream>>>(uoff, udeg, csr_col, invdeg,
                                              (l == 0) ? it16 : it16, u16);
        if (l == 0) {
            // layer 0 consumed the converted item_table already in it16
        }
        gather_it<<<iblocks, 256, 0, stream>>>(ioff, ideg, csc_row, invdeg, u16, it16);
    }

    score_kernel<<<BATCH / 4, 256, 0, stream>>>(u16, it16, uidx, iidx, out);
}

// Round 6
// 601.323 us; speedup vs baseline: 26.6497x; 2.6178x over previous
//
#include <hip/hip_runtime.h>
#include <math.h>

#define NUM_USERS 100000
#define NUM_ITEMS 50000
#define EMBED     64
#define NUM_EDGES 3276800
#define BATCH     16384

typedef _Float16 half8 __attribute__((ext_vector_type(8)));

__device__ __forceinline__ void acc_add(float* acc, half8 x, bool pred) {
    if (pred) {
        #pragma unroll
        for (int j = 0; j < 8; ++j) acc[j] += (float)x[j];
    }
}

__device__ __forceinline__ void acc_add_w(float* acc, half8 x, float v, bool pred) {
    if (pred) {
        #pragma unroll
        for (int j = 0; j < 8; ++j) acc[j] += v * (float)x[j];
    }
}

// ---------- fp32 -> fp16 convert of item table ----------
__global__ void cvt_kernel(const float* __restrict__ in, _Float16* __restrict__ out, int n8) {
    int i = blockIdx.x * 256 + threadIdx.x;
    if (i >= n8) return;
    const float4* p = (const float4*)in + 2 * i;
    float4 a = p[0], b = p[1];
    half8 o;
    o[0] = (_Float16)a.x; o[1] = (_Float16)a.y; o[2] = (_Float16)a.z; o[3] = (_Float16)a.w;
    o[4] = (_Float16)b.x; o[5] = (_Float16)b.y; o[6] = (_Float16)b.z; o[7] = (_Float16)b.w;
    ((half8*)out)[i] = o;
}

// ---------- pass 0: coarse-bucket totals (512 bins each side) ----------
__global__ void pass0_kernel(const int* __restrict__ rows, const int* __restrict__ cols,
                             int* __restrict__ ubins, int* __restrict__ ibins) {
    __shared__ int hu[512], hi[512];
    int t = threadIdx.x;
    hu[t] = 0; hu[t + 256] = 0; hi[t] = 0; hi[t + 256] = 0;
    __syncthreads();
    int e0 = blockIdx.x * 4096;
    for (int i = t; i < 4096; i += 256) {
        int r = rows[e0 + i];
        int c = cols[e0 + i];
        atomicAdd(&hu[r >> 8], 1);
        atomicAdd(&hi[c >> 8], 1);
    }
    __syncthreads();
    int v;
    v = hu[t];       if (v) atomicAdd(&ubins[t], v);
    v = hu[t + 256]; if (v) atomicAdd(&ubins[t + 256], v);
    v = hi[t];       if (v) atomicAdd(&ibins[t], v);
    v = hi[t + 256]; if (v) atomicAdd(&ibins[t + 256], v);
}

// ---------- scan bucket totals -> bases + cursors (one block, 512 threads) ----------
__global__ void scan_bins_kernel(const int* __restrict__ ubins, const int* __restrict__ ibins,
                                 int* __restrict__ ubase, int* __restrict__ ucur,
                                 int* __restrict__ ibase, int* __restrict__ icur) {
    __shared__ int s[512];
    int t = threadIdx.x;
    int v = ubins[t]; s[t] = v; __syncthreads();
    for (int o = 1; o < 512; o <<= 1) {
        int x = (t >= o) ? s[t - o] : 0; __syncthreads();
        s[t] += x; __syncthreads();
    }
    int excl = s[t] - v;
    ubase[t] = excl; ucur[t] = excl;
    if (t == 511) ubase[512] = s[511];
    __syncthreads();
    v = ibins[t]; s[t] = v; __syncthreads();
    for (int o = 1; o < 512; o <<= 1) {
        int x = (t >= o) ? s[t - o] : 0; __syncthreads();
        s[t] += x; __syncthreads();
    }
    excl = s[t] - v;
    ibase[t] = excl; icur[t] = excl;
    if (t == 511) ibase[512] = s[511];
}

// ---------- pass 1: bucket edges into packed records ----------
// rec = (payload << 8) | (key & 255); bucket = key >> 8.
__global__ void pass1_kernel(const int* __restrict__ keys, const int* __restrict__ pay,
                             int* __restrict__ cur, int* __restrict__ rec) {
    __shared__ int h[512], base[512], loc[512];
    int t = threadIdx.x;
    h[t] = 0; h[t + 256] = 0; loc[t] = 0; loc[t + 256] = 0;
    __syncthreads();
    int e0 = blockIdx.x * 4096;
    for (int i = t; i < 4096; i += 256)
        atomicAdd(&h[keys[e0 + i] >> 8], 1);
    __syncthreads();
    int v;
    v = h[t];       base[t]       = v ? atomicAdd(&cur[t], v) : 0;
    v = h[t + 256]; base[t + 256] = v ? atomicAdd(&cur[t + 256], v) : 0;
    __syncthreads();
    for (int i = t; i < 4096; i += 256) {
        int k = keys[e0 + i];
        int p = pay[e0 + i];
        int b = k >> 8;
        int rnk = atomicAdd(&loc[b], 1);
        rec[base[b] + rnk] = (p << 8) | (k & 255);
    }
}

// ---------- pass 2: per-bucket fine sort (256 sub-keys) ----------
__global__ void pass2_kernel(const int* __restrict__ rec, const int* __restrict__ base,
                             int ncap, int* __restrict__ outArr,
                             int* __restrict__ deg, int* __restrict__ off,
                             float* __restrict__ inv) {
    __shared__ int h[256], ex[256], cnt[256], sc[256];
    int t = threadIdx.x, b = blockIdx.x;
    int s = base[b], e = base[b + 1];
    h[t] = 0; cnt[t] = 0;
    __syncthreads();
    for (int i = s + t; i < e; i += 256)
        atomicAdd(&h[rec[i] & 255], 1);
    __syncthreads();
    int v = h[t]; sc[t] = v; __syncthreads();
    for (int o = 1; o < 256; o <<= 1) {
        int x = (t >= o) ? sc[t - o] : 0; __syncthreads();
        sc[t] += x; __syncthreads();
    }
    ex[t] = sc[t] - v;
    int id = b * 256 + t;
    if (id < ncap) {
        deg[id] = v;
        off[id] = s + ex[t];
        if (inv) inv[id] = v ? 1.0f / (float)v : 0.0f;
    }
    __syncthreads();
    for (int i = s + t; i < e; i += 256) {
        int r = rec[i];
        int k = r & 255;
        int rnk = atomicAdd(&cnt[k], 1);
        outArr[s + ex[k] + rnk] = (int)(((unsigned)r) >> 8);
    }
}

// ---------- gather SpMM (u): wave = row, 8 edge-slots x 8 lanes x half8, 4-deep MLP ----------
__global__ void gather_u(const int* __restrict__ uoff, const int* __restrict__ udeg,
                         const int* __restrict__ csr_col, const float* __restrict__ invdeg,
                         const _Float16* __restrict__ it, _Float16* __restrict__ u) {
    int row = blockIdx.x * 4 + (threadIdx.x >> 6);
    if (row >= NUM_USERS) return;
    int lane = threadIdx.x & 63;
    int slot = lane >> 3;
    int h    = lane & 7;
    int start = uoff[row];
    int end = start + udeg[row];
    float acc[8] = {0.f, 0.f, 0.f, 0.f, 0.f, 0.f, 0.f, 0.f};
    for (int k = start; k < end; k += 32) {
        int e1 = end - 1;
        int i0 = k + slot, i1 = i0 + 8, i2 = i0 + 16, i3 = i0 + 24;
        int c0 = csr_col[i0 < e1 ? i0 : e1];
        int c1 = csr_col[i1 < e1 ? i1 : e1];
        int c2 = csr_col[i2 < e1 ? i2 : e1];
        int c3 = csr_col[i3 < e1 ? i3 : e1];
        half8 x0 = *(const half8*)(it + (long long)c0 * EMBED + (h << 3));
        half8 x1 = *(const half8*)(it + (long long)c1 * EMBED + (h << 3));
        half8 x2 = *(const half8*)(it + (long long)c2 * EMBED + (h << 3));
        half8 x3 = *(const half8*)(it + (long long)c3 * EMBED + (h << 3));
        acc_add(acc, x0, i0 < end);
        acc_add(acc, x1, i1 < end);
        acc_add(acc, x2, i2 < end);
        acc_add(acc, x3, i3 < end);
    }
    #pragma unroll
    for (int j = 0; j < 8; ++j) {
        acc[j] += __shfl_xor(acc[j], 8, 64);
        acc[j] += __shfl_xor(acc[j], 16, 64);
        acc[j] += __shfl_xor(acc[j], 32, 64);
    }
    if (lane < 8) {
        float v = invdeg[row];
        half8 o;
        #pragma unroll
        for (int j = 0; j < 8; ++j) o[j] = (_Float16)(acc[j] * v);
        *(half8*)(u + (long long)row * EMBED + (lane << 3)) = o;
    }
}

// ---------- gather SpMM (it): per-edge invdeg weight, 4-deep MLP ----------
__global__ void gather_it(const int* __restrict__ ioff, const int* __restrict__ ideg,
                          const int* __restrict__ csc_row, const float* __restrict__ invdeg,
                          const _Float16* __restrict__ u, _Float16* __restrict__ it) {
    int col = blockIdx.x * 4 + (threadIdx.x >> 6);
    if (col >= NUM_ITEMS) return;
    int lane = threadIdx.x & 63;
    int slot = lane >> 3;
    int h    = lane & 7;
    int start = ioff[col];
    int end = start + ideg[col];
    float acc[8] = {0.f, 0.f, 0.f, 0.f, 0.f, 0.f, 0.f, 0.f};
    for (int k = start; k < end; k += 32) {
        int e1 = end - 1;
        int i0 = k + slot, i1 = i0 + 8, i2 = i0 + 16, i3 = i0 + 24;
        int r0 = csc_row[i0 < e1 ? i0 : e1];
        int r1 = csc_row[i1 < e1 ? i1 : e1];
        int r2 = csc_row[i2 < e1 ? i2 : e1];
        int r3 = csc_row[i3 < e1 ? i3 : e1];
        float v0 = invdeg[r0], v1 = invdeg[r1], v2 = invdeg[r2], v3 = invdeg[r3];
        half8 x0 = *(const half8*)(u + (long long)r0 * EMBED + (h << 3));
        half8 x1 = *(const half8*)(u + (long long)r1 * EMBED + (h << 3));
        half8 x2 = *(const half8*)(u + (long long)r2 * EMBED + (h << 3));
        half8 x3 = *(const half8*)(u + (long long)r3 * EMBED + (h << 3));
        acc_add_w(acc, x0, v0, i0 < end);
        acc_add_w(acc, x1, v1, i1 < end);
        acc_add_w(acc, x2, v2, i2 < end);
        acc_add_w(acc, x3, v3, i3 < end);
    }
    #pragma unroll
    for (int j = 0; j < 8; ++j) {
        acc[j] += __shfl_xor(acc[j], 8, 64);
        acc[j] += __shfl_xor(acc[j], 16, 64);
        acc[j] += __shfl_xor(acc[j], 32, 64);
    }
    if (lane < 8) {
        half8 o;
        #pragma unroll
        for (int j = 0; j < 8; ++j) o[j] = (_Float16)acc[j];
        *(half8*)(it + (long long)col * EMBED + (lane << 3)) = o;
    }
}

// ---------- scores ----------
__global__ void score_kernel(const _Float16* __restrict__ u, const _Float16* __restrict__ it,
                             const int* __restrict__ uidx, const int* __restrict__ iidx,
                             float* __restrict__ out) {
    int wave_in_block = threadIdx.x >> 6;
    int lane = threadIdx.x & 63;
    int b = blockIdx.x * 4 + wave_in_block;
    if (b >= BATCH) return;
    int ui = uidx[b];
    int ii = iidx[b];
    float s = (float)u[(long long)ui * EMBED + lane] * (float)it[(long long)ii * EMBED + lane];
    #pragma unroll
    for (int off = 32; off > 0; off >>= 1)
        s += __shfl_down(s, off, 64);
    if (lane == 0)
        out[b] = 1.0f / (1.0f + expf(-s));
}

extern "C" void kernel_launch(void* const* d_in, const int* in_sizes, int n_in,
                              void* d_out, int out_size, void* d_ws, size_t ws_size,
                              hipStream_t stream) {
    const float* item_table = (const float*)d_in[1];
    const int*   rows       = (const int*)d_in[2];
    const int*   cols       = (const int*)d_in[3];
    const int*   uidx       = (const int*)d_in[4];
    const int*   iidx       = (const int*)d_in[5];
    float* out = (float*)d_out;

    // workspace layout (byte offsets)
    char* base = (char*)d_ws;
    float* invdeg = (float*)(base + 0);              // 100000 f
    int*   udeg   = (int*)(base +   400000);         // 100000 i
    int*   ideg   = (int*)(base +   800000);         // 50000 i
    int*   uoff   = (int*)(base +  1000000);         // 100000 i
    int*   ioff   = (int*)(base +  1400000);         // 50000 i
    int*   ubins  = (int*)(base +  1600000);         // 512 i
    int*   ibins  = (int*)(base +  1602048);         // 512 i
    int*   ubase  = (int*)(base +  1604096);         // 513 i
    int*   ibase  = (int*)(base +  1608192);         // 513 i
    int*   ucur   = (int*)(base +  1612288);         // 512 i
    int*   icur   = (int*)(base +  1614336);         // 512 i
    int*   rec    = (int*)(base +  2000000);         // NUM_EDGES i (13.1 MB, reused CSR->CSC)
    int*   csr_col= (int*)(base + 15107200);         // NUM_EDGES i
    int*   csc_row= (int*)(base + 28214400);         // NUM_EDGES i
    _Float16* u16 = (_Float16*)(base + 41321600);    // 100000*64 h (12.8 MB)
    _Float16* it16= (_Float16*)(base + 54121600);    // 50000*64 h (6.4 MB)

    (void)hipMemsetAsync(ubins, 0, 4096, stream);    // ubins + ibins contiguous

    cvt_kernel<<<(NUM_ITEMS * EMBED / 8 + 255) / 256, 256, 0, stream>>>(
        item_table, it16, NUM_ITEMS * EMBED / 8);

    // ---- build CSR + CSC (line-dense bucket sort, no per-edge scattered stores) ----
    pass0_kernel<<<800, 256, 0, stream>>>(rows, cols, ubins, ibins);
    scan_bins_kernel<<<1, 512, 0, stream>>>(ubins, ibins, ubase, ucur, ibase, icur);

    pass1_kernel<<<800, 256, 0, stream>>>(rows, cols, ucur, rec);
    pass2_kernel<<<391, 256, 0, stream>>>(rec, ubase, NUM_USERS, csr_col,
                                          udeg, uoff, invdeg);
    pass1_kernel<<<800, 256, 0, stream>>>(cols, rows, icur, rec);
    pass2_kernel<<<196, 256, 0, stream>>>(rec, ibase, NUM_ITEMS, csc_row,
                                          ideg, ioff, (float*)nullptr);

    // ---- propagation ----
    const int ublocks = (NUM_USERS + 3) / 4;
    const int iblocks = (NUM_ITEMS + 3) / 4;
    for (int l = 0; l < 3; ++l) {
        gather_u<<<ublocks, 256, 0, stream>>>(uoff, udeg, csr_col, invdeg, it16, u16);
        gather_it<<<iblocks, 256, 0, stream>>>(ioff, ideg, csc_row, invdeg, u16, it16);
    }

    score_kernel<<<BATCH / 4, 256, 0, stream>>>(u16, it16, uidx, iidx, out);
}